// Round 19
// baseline (128.711 us; speedup 1.0000x reference)
//
#include <hip/hip_runtime.h>
#include <stdint.h>

// Binarized dense via i8 MFMA: C[r][u] = dot(sign(x[r,:]), sign(W[:,u])) + b[u]
// sign in {+1,-1} as i8 0x01/0xFF; i32 accumulation exact (|dot| <= 4096).
// v_mfma_i32_32x32x32_i8: A/B = v4i (16 i8), lane&31 = row/col, lane>>5 =
// k-16-half; C/D: col = lane&31, row = (r&3)+8*(r>>2)+4*(lane>>5).
// Layouts/maps HW-verified (rounds 12-18, absmax 0).
//
// v15 = TRAFFIC redesign. r13-r18 established: schedule shuffles at fixed
// traffic move <5%; occupancy beyond 16 waves/CU doesn't help; per-CU
// per-step pipe SUM (LDS A-reads 64KB + B-VMEM 64KB + x + MFMA) ~= measured
// step time. So cut the traffic:
//  - wave = 64 rows x 32 cols (2 stacked 32x32 tiles): per step 4 MFMA but
//    only 4 A-frags + 2 B-frags (r15: 8 A-frags + 4 B-frags for 32x64).
//  - block = 64 rows x 256 cols, 512 thr (8 waves); grid = 256 row-stripes
//    x 2 col-halves = 512 blocks -> 2 blocks/CU.
//  - per-CU/step: LDS A-reads 32 KB, B-VMEM 32 KB (total B 512 MB, was
//    1 GB), x 32 KB (x2 re-read, L3-hot: col-pair blocks dispatch together).
//  - B on demand from L2 (fragment-major Wb2, no B LDS); A-frags in 32 KB
//    LDS quad-period dbuf; 16 barriers.
// VGPR ~110 (acc 32 + xq 32 + transients) < 128 cap (512-thr, (512,1)).

#define BATCH  16384
#define UNITS  512
#define KDIM   4096
#define KSTEP  64
#define NSTEP  (KDIM / KSTEP)   // 64
#define NPER   (NSTEP / 4)      // 16 quad-periods
#define MROWS  64               // rows per block
#define NCOLS  256              // cols per block

typedef int v4i  __attribute__((ext_vector_type(4)));
typedef int v16i __attribute__((ext_vector_type(16)));

// ---- pack W: f32 [4096][512] -> Wb2 fragment-major i8 +/-1 (2 MB) ----------
// 16B chunk index ((s*16 + n5)*2 + ks)*64 + lane; lane = (n&31) + 32*k16half;
// covers col n5*32+(n&31), k = s*64 + ks*32 + k16half*16 + [0..15].
__global__ __launch_bounds__(256) void pack_w_kernel(const float* __restrict__ W,
                                                     uint8_t* __restrict__ Wb2) {
    int t  = blockIdx.x * 256 + threadIdx.x;   // 0..262143
    int n  = t & 511;                          // col
    int k0 = (t >> 9) * 8;                     // 8 consecutive k
    unsigned long long m = 0;
    #pragma unroll
    for (int j = 0; j < 8; ++j) {
        float v = W[(size_t)(k0 + j) * UNITS + n];
        m |= ((v < 0.f) ? 0xFFull : 0x01ull) << (8 * j);
    }
    int s  = k0 >> 6;
    int kk = k0 & 63;
    int ks = kk >> 5;
    int hi = (kk & 31) >> 4;
    int lane = (n & 31) + 32 * hi;
    size_t a = ((((size_t)s * 16 + (n >> 5)) * 2 + ks) * 64 + lane) * 16 + (kk & 15);
    *reinterpret_cast<unsigned long long*>(Wb2 + a) = m;
}

__device__ __forceinline__ uint32_t sgn4(float4 v) {
    uint32_t b0 = v.x < 0.f ? 0xFFu : 0x01u;
    uint32_t b1 = v.y < 0.f ? 0xFFu : 0x01u;
    uint32_t b2 = v.z < 0.f ? 0xFFu : 0x01u;
    uint32_t b3 = v.w < 0.f ? 0xFFu : 0x01u;
    return b0 | (b1 << 8) | (b2 << 16) | (b3 << 24);
}

// Af step-block layout (per buf 16 KB, per sip 4 KB):
//   byte = PB*16384 + sip*4096 + rt*2048 + ks*1024 + lane16*16 + off
//   lane16 = (row&31) + 32*k16half  (verified A-frag map)

// one K-step: 2 B-frags on demand (L2), 4 A-frags (2 rt x 2 ks), 4 MFMA
#define STEP(PB, SIP, Q)                                                       \
    {                                                                          \
        const uint8_t* _b = bbase + (size_t)(4 * (Q) + (SIP)) * 32768;         \
        v4i b0 = *reinterpret_cast<const v4i*>(_b);                            \
        v4i b1 = *reinterpret_cast<const v4i*>(_b + 1024);                     \
        const uint8_t* _a = &Af[(PB) * 16384 + (SIP) * 4096 + l * 16];         \
        v4i a00 = *reinterpret_cast<const v4i*>(_a);                           \
        v4i a01 = *reinterpret_cast<const v4i*>(_a + 1024);                    \
        v4i a10 = *reinterpret_cast<const v4i*>(_a + 2048);                    \
        v4i a11 = *reinterpret_cast<const v4i*>(_a + 3072);                    \
        __builtin_amdgcn_s_setprio(1);                                         \
        acc0 = __builtin_amdgcn_mfma_i32_32x32x32_i8(a00, b0, acc0, 0, 0, 0);  \
        acc0 = __builtin_amdgcn_mfma_i32_32x32x32_i8(a01, b1, acc0, 0, 0, 0);  \
        acc1 = __builtin_amdgcn_mfma_i32_32x32x32_i8(a10, b0, acc1, 0, 0, 0);  \
        acc1 = __builtin_amdgcn_mfma_i32_32x32x32_i8(a11, b1, acc1, 0, 0, 0);  \
        __builtin_amdgcn_s_setprio(0);                                         \
    }

// load this thread's 2 x-float4s (rows trow, trow+32) of absolute step S
#define XLD2(XA, XB, S)                                                        \
    {                                                                          \
        const int _sc = ((S) < NSTEP) ? (S) : NSTEP - 1;                       \
        XA = *reinterpret_cast<const float4*>(xr0 + (size_t)_sc * KSTEP);      \
        XB = *reinterpret_cast<const float4*>(xr0 + (size_t)32 * KDIM          \
                                                  + (size_t)_sc * KSTEP);      \
    }

// commit the pair into Af[PB], step-slot SIP (rt 0 and 1)
#define XCM2(PB, SIP, XA, XB)                                                  \
    {                                                                          \
        *reinterpret_cast<uint32_t*>(                                          \
            &Af[(PB) * 16384 + (SIP) * 4096 + awk]) = sgn4(XA);                \
        *reinterpret_cast<uint32_t*>(                                          \
            &Af[(PB) * 16384 + (SIP) * 4096 + 2048 + awk]) = sgn4(XB);         \
    }

// one quad-period: steps 4Q..4Q+3 read Af[PB]; commits A(4Q+4..+7) -> Af[PB^1]
#define PERIOD(Q, PB)                                                          \
    {                                                                          \
        float4 xa0, xb0, xa1, xb1, xa2, xb2, xa3, xb3;                         \
        STEP(PB, 0, Q); XLD2(xa0, xb0, 4 * (Q) + 4);                           \
        STEP(PB, 1, Q); XLD2(xa1, xb1, 4 * (Q) + 5);                           \
        STEP(PB, 2, Q); XLD2(xa2, xb2, 4 * (Q) + 6);                           \
        STEP(PB, 3, Q); XLD2(xa3, xb3, 4 * (Q) + 7);                           \
        XCM2((PB) ^ 1, 0, xa0, xb0);                                           \
        XCM2((PB) ^ 1, 1, xa1, xb1);                                           \
        XCM2((PB) ^ 1, 2, xa2, xb2);                                           \
        XCM2((PB) ^ 1, 3, xa3, xb3);                                           \
        __syncthreads();                                                       \
    }

// ------------------------------- MFMA GEMM ----------------------------------
__global__ __launch_bounds__(512, 1) void mm_kernel(const float* __restrict__ x,
                                                    const uint8_t* __restrict__ Wb2,
                                                    const float* __restrict__ bias,
                                                    float* __restrict__ C) {
    __shared__ __attribute__((aligned(16))) uint8_t Af[2 * 16384];  // 32 KB
    const int t   = threadIdx.x;
    const int l   = t & 63;
    const int wv  = t >> 6;              // wave 0..7 -> cols cb0 + wv*32..+31
    const int lr  = l & 31;
    const int hi  = l >> 5;
    const int bx  = blockIdx.x;
    const int row0 = (bx >> 1) * MROWS;  // 64-row stripe
    const int cb8  = (bx & 1) * 8;       // col-group base (8 groups of 32)

    // x staging: thread t owns rows trow & trow+32, float4 at k-offset tak
    const int trow = t >> 4;             // 0..31
    const int tak  = (t & 15) * 4;       // 0..60
    // Af in-step write offset (rt added separately): verified lane16 map
    const int awk = (tak >> 5) * 1024
                  + (trow + 32 * ((tak >> 4) & 1)) * 16 + (tak & 15);
    const float* xr0 = x + (size_t)(row0 + trow) * KDIM + tak;
    const uint8_t* bbase = Wb2 + (size_t)(cb8 + wv) * 2048 + (size_t)l * 16;

    v16i acc0, acc1;
    #pragma unroll
    for (int e = 0; e < 16; ++e) { acc0[e] = 0; acc1[e] = 0; }

    // ---- prologue: stage steps 0..3 into Af[0] ----
    {
        float4 xa, xb;
        XLD2(xa, xb, 0); XCM2(0, 0, xa, xb);
        XLD2(xa, xb, 1); XCM2(0, 1, xa, xb);
        XLD2(xa, xb, 2); XCM2(0, 2, xa, xb);
        XLD2(xa, xb, 3); XCM2(0, 3, xa, xb);
        __syncthreads();
    }

    #pragma unroll 1
    for (int q = 0; q < NPER; q += 2) {
        PERIOD(q,     0);
        PERIOD(q + 1, 1);
    }

    // ---- epilogue: C = acc + bias (verified C/D map) ----
    {
        const int col = cb8 * 32 + wv * 32 + lr;
        const float bv = bias[col];
        #pragma unroll
        for (int r = 0; r < 16; ++r) {
            int crow = (r & 3) + 8 * (r >> 2) + 4 * hi;
            C[(size_t)(row0 + crow) * UNITS + col]      = (float)acc0[r] + bv;
            C[(size_t)(row0 + 32 + crow) * UNITS + col] = (float)acc1[r] + bv;
        }
    }
}

extern "C" void kernel_launch(void* const* d_in, const int* in_sizes, int n_in,
                              void* d_out, int out_size, void* d_ws, size_t ws_size,
                              hipStream_t stream) {
    const float* x = (const float*)d_in[0];
    const float* W = (const float*)d_in[1];
    const float* b = (const float*)d_in[2];
    float* out = (float*)d_out;

    uint8_t* Wb2 = (uint8_t*)d_ws;   // 2 MB fragment-major packed W

    pack_w_kernel<<<(512 * 512) / 256, 256, 0, stream>>>(W, Wb2);
    mm_kernel<<<(BATCH / MROWS) * (UNITS / NCOLS), 512, 0, stream>>>(
        x, Wb2, b, out);
}

// Round 20
// 94.075 us; speedup vs baseline: 1.3682x; 1.3682x over previous
//
#include <hip/hip_runtime.h>
#include <stdint.h>

// Binarized dense via i8 MFMA: C[r][u] = dot(sign(x[r,:]), sign(W[:,u])) + b[u]
// sign in {+1,-1} as i8 0x01/0xFF; i32 accumulation exact (|dot| <= 4096).
// v_mfma_i32_32x32x32_i8: A/B = v4i (16 i8), lane&31 = row/col, lane>>5 =
// k-16-half; C/D: col = lane&31, row = (r&3)+8*(r>>2)+4*(lane>>5).
// Layouts/maps HW-verified (rounds 12-19, absmax 0).
//
// v16 = B-DEDUP design. Traffic model (validated by r15/r18/r19 ordering):
// step time ~ serialized sum of B-L1 + x-HBM + A-LDS + MFMA per CU.
// r15 (2 blk/CU) pulls the same 32KB B tile twice -> 64KB B/step/CU.
// Here: block = 64 rows x 512 cols (512 thr), wave = 64x64 (2x2 32-tiles,
// acc 64 VGPR), grid 256 -> 1 block/CU:
//   B 32KB/step/CU (halved), x 16KB (read once, no col-split),
//   A-LDS 32KB (shared frags, rt-stacked), MFMA unchanged.
// vs r12's failed 1-blk/CU: B stays in REGISTERS (on demand from L2,
// fragment-major Wb2), LDS is 32KB A-only, 16 barriers total.
// x: named 2-pair cross-period pipeline, committed with 2-cluster slack.
// VGPR ~124 <= 128 cap (512-thr blocks, alloc-to-demand).

#define BATCH  16384
#define UNITS  512
#define KDIM   4096
#define KSTEP  64
#define NSTEP  (KDIM / KSTEP)   // 64
#define NPER   (NSTEP / 4)      // 16 quad-periods
#define MROWS  64               // rows per block

typedef int v4i  __attribute__((ext_vector_type(4)));
typedef int v16i __attribute__((ext_vector_type(16)));

// ---- pack W: f32 [4096][512] -> Wb2 fragment-major i8 +/-1 (2 MB) ----------
// 16B chunk index ((s*16 + n5)*2 + ks)*64 + lane; lane = (n&31) + 32*k16half;
// covers col n5*32+(n&31), k = s*64 + ks*32 + k16half*16 + [0..15].
__global__ __launch_bounds__(256) void pack_w_kernel(const float* __restrict__ W,
                                                     uint8_t* __restrict__ Wb2) {
    int t  = blockIdx.x * 256 + threadIdx.x;   // 0..262143
    int n  = t & 511;                          // col
    int k0 = (t >> 9) * 8;                     // 8 consecutive k
    unsigned long long m = 0;
    #pragma unroll
    for (int j = 0; j < 8; ++j) {
        float v = W[(size_t)(k0 + j) * UNITS + n];
        m |= ((v < 0.f) ? 0xFFull : 0x01ull) << (8 * j);
    }
    int s  = k0 >> 6;
    int kk = k0 & 63;
    int ks = kk >> 5;
    int hi = (kk & 31) >> 4;
    int lane = (n & 31) + 32 * hi;
    size_t a = ((((size_t)s * 16 + (n >> 5)) * 2 + ks) * 64 + lane) * 16 + (kk & 15);
    *reinterpret_cast<unsigned long long*>(Wb2 + a) = m;
}

__device__ __forceinline__ uint32_t sgn4(float4 v) {
    uint32_t b0 = v.x < 0.f ? 0xFFu : 0x01u;
    uint32_t b1 = v.y < 0.f ? 0xFFu : 0x01u;
    uint32_t b2 = v.z < 0.f ? 0xFFu : 0x01u;
    uint32_t b3 = v.w < 0.f ? 0xFFu : 0x01u;
    return b0 | (b1 << 8) | (b2 << 16) | (b3 << 24);
}

// Af layout (verified r19): byte = PB*16384 + sip*4096 + rt*2048 + ks*1024
//                                + ((row&31) + 32*k16half)*16 + off

// one K-step: 4 B-frags on demand (L2), 4 A-frags (2rt x 2ks), 8 MFMA
#define STEP(PB, SIP, Q)                                                       \
    {                                                                          \
        const uint8_t* _b = bbase + (size_t)(4 * (Q) + (SIP)) * 32768;         \
        v4i b0 = *reinterpret_cast<const v4i*>(_b);            /* ct0 ks0 */   \
        v4i b1 = *reinterpret_cast<const v4i*>(_b + 1024);     /* ct0 ks1 */   \
        v4i b2 = *reinterpret_cast<const v4i*>(_b + 2048);     /* ct1 ks0 */   \
        v4i b3 = *reinterpret_cast<const v4i*>(_b + 3072);     /* ct1 ks1 */   \
        const uint8_t* _a = &Af[(PB) * 16384 + (SIP) * 4096 + l * 16];         \
        v4i a00 = *reinterpret_cast<const v4i*>(_a);           /* rt0 ks0 */   \
        v4i a01 = *reinterpret_cast<const v4i*>(_a + 1024);    /* rt0 ks1 */   \
        v4i a10 = *reinterpret_cast<const v4i*>(_a + 2048);    /* rt1 ks0 */   \
        v4i a11 = *reinterpret_cast<const v4i*>(_a + 3072);    /* rt1 ks1 */   \
        __builtin_amdgcn_s_setprio(1);                                         \
        acc00 = __builtin_amdgcn_mfma_i32_32x32x32_i8(a00, b0, acc00, 0, 0, 0);\
        acc00 = __builtin_amdgcn_mfma_i32_32x32x32_i8(a01, b1, acc00, 0, 0, 0);\
        acc01 = __builtin_amdgcn_mfma_i32_32x32x32_i8(a00, b2, acc01, 0, 0, 0);\
        acc01 = __builtin_amdgcn_mfma_i32_32x32x32_i8(a01, b3, acc01, 0, 0, 0);\
        acc10 = __builtin_amdgcn_mfma_i32_32x32x32_i8(a10, b0, acc10, 0, 0, 0);\
        acc10 = __builtin_amdgcn_mfma_i32_32x32x32_i8(a11, b1, acc10, 0, 0, 0);\
        acc11 = __builtin_amdgcn_mfma_i32_32x32x32_i8(a10, b2, acc11, 0, 0, 0);\
        acc11 = __builtin_amdgcn_mfma_i32_32x32x32_i8(a11, b3, acc11, 0, 0, 0);\
        __builtin_amdgcn_s_setprio(0);                                         \
    }

// load this thread's 2 x-float4s (rows trow, trow+32) of absolute step S
#define XLD2(XA, XB, S)                                                        \
    {                                                                          \
        const int _sc = ((S) < NSTEP) ? (S) : NSTEP - 1;                       \
        XA = *reinterpret_cast<const float4*>(xr0 + (size_t)_sc * KSTEP);      \
        XB = *reinterpret_cast<const float4*>(xr0 + (size_t)32 * KDIM          \
                                                  + (size_t)_sc * KSTEP);      \
    }

// commit the pair into Af[PB], step-slot SIP (rt 0 and 1)
#define XCM2(PB, SIP, XA, XB)                                                  \
    {                                                                          \
        *reinterpret_cast<uint32_t*>(                                          \
            &Af[(PB) * 16384 + (SIP) * 4096 + awk]) = sgn4(XA);                \
        *reinterpret_cast<uint32_t*>(                                          \
            &Af[(PB) * 16384 + (SIP) * 4096 + 2048 + awk]) = sgn4(XB);         \
    }

// one quad-period: steps 4Q..4Q+3 read Af[PB]; commits A(4Q+4..+7) -> Af[PB^1]
// steady state: entering PERIOD(Q), (xA0,xA1) holds step 4Q+4 data.
#define PERIOD(Q, PB)                                                          \
    {                                                                          \
        STEP(PB, 0, Q);                                                        \
        XLD2(xB0, xB1, 4 * (Q) + 5);                                           \
        STEP(PB, 1, Q);                                                        \
        XCM2((PB) ^ 1, 0, xA0, xA1);                                           \
        XLD2(xA0, xA1, 4 * (Q) + 6);                                           \
        STEP(PB, 2, Q);                                                        \
        XCM2((PB) ^ 1, 1, xB0, xB1);                                           \
        XLD2(xB0, xB1, 4 * (Q) + 7);                                           \
        STEP(PB, 3, Q);                                                        \
        XCM2((PB) ^ 1, 2, xA0, xA1);                                           \
        XLD2(xA0, xA1, 4 * (Q) + 8);   /* = 4(Q+1)+4: next period's sip0 */    \
        XCM2((PB) ^ 1, 3, xB0, xB1);                                           \
        __syncthreads();                                                       \
    }

// ------------------------------- MFMA GEMM ----------------------------------
__global__ __launch_bounds__(512, 1) void mm_kernel(const float* __restrict__ x,
                                                    const uint8_t* __restrict__ Wb2,
                                                    const float* __restrict__ bias,
                                                    float* __restrict__ C) {
    __shared__ __attribute__((aligned(16))) uint8_t Af[2 * 16384];  // 32 KB
    const int t   = threadIdx.x;
    const int l   = t & 63;
    const int wv  = t >> 6;              // wave 0..7 -> cols wv*64..+63
    const int lr  = l & 31;
    const int hi  = l >> 5;
    const int row0 = blockIdx.x * MROWS;

    // x staging (verified r19): thread t owns rows trow & trow+32, f4 at tak
    const int trow = t >> 4;             // 0..31
    const int tak  = (t & 15) * 4;       // 0..60
    const int awk = (tak >> 5) * 1024
                  + (trow + 32 * ((tak >> 4) & 1)) * 16 + (tak & 15);
    const float* xr0 = x + (size_t)(row0 + trow) * KDIM + tak;
    // B base (verified r15): n5 = wv*2 + ct; ct stride 2048, ks stride 1024
    const uint8_t* bbase = Wb2 + ((size_t)(wv * 2) * 2 * 64 + l) * 16;

    v16i acc00, acc01, acc10, acc11;
    #pragma unroll
    for (int e = 0; e < 16; ++e) { acc00[e] = 0; acc01[e] = 0;
                                   acc10[e] = 0; acc11[e] = 0; }

    float4 xA0, xA1, xB0, xB1;

    // ---- prologue: stage steps 0..3 into Af[0]; preload xA = step 4 ----
    {
        float4 xa, xb;
        XLD2(xa, xb, 0); XCM2(0, 0, xa, xb);
        XLD2(xa, xb, 1); XCM2(0, 1, xa, xb);
        XLD2(xa, xb, 2); XCM2(0, 2, xa, xb);
        XLD2(xa, xb, 3); XCM2(0, 3, xa, xb);
        XLD2(xA0, xA1, 4);
        __syncthreads();
    }

    #pragma unroll 1
    for (int q = 0; q < NPER; q += 2) {
        PERIOD(q,     0);
        PERIOD(q + 1, 1);
    }

    // ---- epilogue: C = acc + bias (verified C/D map) ----
    {
        const int col0 = wv * 64 + lr;          // ct = 0
        const int col1 = wv * 64 + 32 + lr;     // ct = 1
        const float bv0 = bias[col0], bv1 = bias[col1];
        #pragma unroll
        for (int r = 0; r < 16; ++r) {
            int crow = (r & 3) + 8 * (r >> 2) + 4 * hi;
            C[(size_t)(row0 + crow) * UNITS + col0]      = (float)acc00[r] + bv0;
            C[(size_t)(row0 + crow) * UNITS + col1]      = (float)acc01[r] + bv1;
            C[(size_t)(row0 + 32 + crow) * UNITS + col0] = (float)acc10[r] + bv0;
            C[(size_t)(row0 + 32 + crow) * UNITS + col1] = (float)acc11[r] + bv1;
        }
    }
}

extern "C" void kernel_launch(void* const* d_in, const int* in_sizes, int n_in,
                              void* d_out, int out_size, void* d_ws, size_t ws_size,
                              hipStream_t stream) {
    const float* x = (const float*)d_in[0];
    const float* W = (const float*)d_in[1];
    const float* b = (const float*)d_in[2];
    float* out = (float*)d_out;

    uint8_t* Wb2 = (uint8_t*)d_ws;   // 2 MB fragment-major packed W

    pack_w_kernel<<<(512 * 512) / 256, 256, 0, stream>>>(W, Wb2);
    mm_kernel<<<BATCH / MROWS, 512, 0, stream>>>(x, Wb2, b, out);
}

// Round 21
// 92.954 us; speedup vs baseline: 1.3847x; 1.0121x over previous
//
#include <hip/hip_runtime.h>
#include <stdint.h>

// Binarized dense via i8 MFMA: C[r][u] = dot(sign(x[r,:]), sign(W[:,u])) + b[u]
// sign in {+1,-1} as i8 0x01/0xFF; i32 accumulation exact (|dot| <= 4096).
// v_mfma_i32_32x32x32_i8: A/B = v4i (16 i8), lane&31 = row/col, lane>>5 =
// k-16-half; C/D: col = lane&31, row = (r&3)+8*(r>>2)+4*(lane>>5).
// Layouts/maps HW-verified (rounds 12-20, absmax 0).
//
// v17 = v16 (r20 best, 94.07us) with NON-DRAINING barriers (T3/T4):
// __syncthreads() lowers to s_waitcnt vmcnt(0) lgkmcnt(0) + s_barrier -> each
// of the 16 period barriers drained the just-issued next-period x loads
// (~800cy whole-CU stall) and cold-restarted every wave's load pipeline.
// Replaced with the split protocol (m201/m218 pattern):
//     s_waitcnt lgkmcnt(0)   ; my ds_writes landed ("memory" clobber pins
//                              preceding LDS ops)
//     s_barrier              ; raw builtin: NO implicit vmcnt drain
//     sched_barrier(0)       ; rule-#18 fence: nothing hoists above
// x/B loads now genuinely span barriers; their vmcnt waits land at the
// sgn4/MFMA consumption points (1-3 clusters after issue).
// Everything else identical to r20: block = 64 rows x 512 cols (512 thr,
// wave = 64x64 = 2x2 32-tiles), grid 256 = 1 block/CU, B on demand from L2
// (fragment-major Wb2, no B LDS), A-frags in 32 KB LDS quad-period dbuf,
// x read from HBM exactly once. VGPR ~124 <= 128 cap.

#define BATCH  16384
#define UNITS  512
#define KDIM   4096
#define KSTEP  64
#define NSTEP  (KDIM / KSTEP)   // 64
#define NPER   (NSTEP / 4)      // 16 quad-periods
#define MROWS  64               // rows per block

typedef int v4i  __attribute__((ext_vector_type(4)));
typedef int v16i __attribute__((ext_vector_type(16)));

// split-protocol barrier: lgkm-drain only; vmcnt loads stay in flight
#define BARRIER()                                                              \
    do {                                                                       \
        asm volatile("s_waitcnt lgkmcnt(0)" ::: "memory");                     \
        __builtin_amdgcn_s_barrier();                                          \
        __builtin_amdgcn_sched_barrier(0);                                     \
    } while (0)

// ---- pack W: f32 [4096][512] -> Wb2 fragment-major i8 +/-1 (2 MB) ----------
// 16B chunk index ((s*16 + n5)*2 + ks)*64 + lane; lane = (n&31) + 32*k16half;
// covers col n5*32+(n&31), k = s*64 + ks*32 + k16half*16 + [0..15].
__global__ __launch_bounds__(256) void pack_w_kernel(const float* __restrict__ W,
                                                     uint8_t* __restrict__ Wb2) {
    int t  = blockIdx.x * 256 + threadIdx.x;   // 0..262143
    int n  = t & 511;                          // col
    int k0 = (t >> 9) * 8;                     // 8 consecutive k
    unsigned long long m = 0;
    #pragma unroll
    for (int j = 0; j < 8; ++j) {
        float v = W[(size_t)(k0 + j) * UNITS + n];
        m |= ((v < 0.f) ? 0xFFull : 0x01ull) << (8 * j);
    }
    int s  = k0 >> 6;
    int kk = k0 & 63;
    int ks = kk >> 5;
    int hi = (kk & 31) >> 4;
    int lane = (n & 31) + 32 * hi;
    size_t a = ((((size_t)s * 16 + (n >> 5)) * 2 + ks) * 64 + lane) * 16 + (kk & 15);
    *reinterpret_cast<unsigned long long*>(Wb2 + a) = m;
}

__device__ __forceinline__ uint32_t sgn4(float4 v) {
    uint32_t b0 = v.x < 0.f ? 0xFFu : 0x01u;
    uint32_t b1 = v.y < 0.f ? 0xFFu : 0x01u;
    uint32_t b2 = v.z < 0.f ? 0xFFu : 0x01u;
    uint32_t b3 = v.w < 0.f ? 0xFFu : 0x01u;
    return b0 | (b1 << 8) | (b2 << 16) | (b3 << 24);
}

// Af layout (verified): byte = PB*16384 + sip*4096 + rt*2048 + ks*1024
//                            + ((row&31) + 32*k16half)*16 + off

// one K-step: 4 B-frags on demand (L2), 4 A-frags (2rt x 2ks), 8 MFMA
#define STEP(PB, SIP, Q)                                                       \
    {                                                                          \
        const uint8_t* _b = bbase + (size_t)(4 * (Q) + (SIP)) * 32768;         \
        v4i b0 = *reinterpret_cast<const v4i*>(_b);            /* ct0 ks0 */   \
        v4i b1 = *reinterpret_cast<const v4i*>(_b + 1024);     /* ct0 ks1 */   \
        v4i b2 = *reinterpret_cast<const v4i*>(_b + 2048);     /* ct1 ks0 */   \
        v4i b3 = *reinterpret_cast<const v4i*>(_b + 3072);     /* ct1 ks1 */   \
        const uint8_t* _a = &Af[(PB) * 16384 + (SIP) * 4096 + l * 16];         \
        v4i a00 = *reinterpret_cast<const v4i*>(_a);           /* rt0 ks0 */   \
        v4i a01 = *reinterpret_cast<const v4i*>(_a + 1024);    /* rt0 ks1 */   \
        v4i a10 = *reinterpret_cast<const v4i*>(_a + 2048);    /* rt1 ks0 */   \
        v4i a11 = *reinterpret_cast<const v4i*>(_a + 3072);    /* rt1 ks1 */   \
        __builtin_amdgcn_s_setprio(1);                                         \
        acc00 = __builtin_amdgcn_mfma_i32_32x32x32_i8(a00, b0, acc00, 0, 0, 0);\
        acc00 = __builtin_amdgcn_mfma_i32_32x32x32_i8(a01, b1, acc00, 0, 0, 0);\
        acc01 = __builtin_amdgcn_mfma_i32_32x32x32_i8(a00, b2, acc01, 0, 0, 0);\
        acc01 = __builtin_amdgcn_mfma_i32_32x32x32_i8(a01, b3, acc01, 0, 0, 0);\
        acc10 = __builtin_amdgcn_mfma_i32_32x32x32_i8(a10, b0, acc10, 0, 0, 0);\
        acc10 = __builtin_amdgcn_mfma_i32_32x32x32_i8(a11, b1, acc10, 0, 0, 0);\
        acc11 = __builtin_amdgcn_mfma_i32_32x32x32_i8(a10, b2, acc11, 0, 0, 0);\
        acc11 = __builtin_amdgcn_mfma_i32_32x32x32_i8(a11, b3, acc11, 0, 0, 0);\
        __builtin_amdgcn_s_setprio(0);                                         \
    }

// load this thread's 2 x-float4s (rows trow, trow+32) of absolute step S
#define XLD2(XA, XB, S)                                                        \
    {                                                                          \
        const int _sc = ((S) < NSTEP) ? (S) : NSTEP - 1;                       \
        XA = *reinterpret_cast<const float4*>(xr0 + (size_t)_sc * KSTEP);      \
        XB = *reinterpret_cast<const float4*>(xr0 + (size_t)32 * KDIM          \
                                                  + (size_t)_sc * KSTEP);      \
    }

// commit the pair into Af[PB], step-slot SIP (rt 0 and 1)
#define XCM2(PB, SIP, XA, XB)                                                  \
    {                                                                          \
        *reinterpret_cast<uint32_t*>(                                          \
            &Af[(PB) * 16384 + (SIP) * 4096 + awk]) = sgn4(XA);                \
        *reinterpret_cast<uint32_t*>(                                          \
            &Af[(PB) * 16384 + (SIP) * 4096 + 2048 + awk]) = sgn4(XB);         \
    }

// one quad-period: steps 4Q..4Q+3 read Af[PB]; commits A(4Q+4..+7) -> Af[PB^1]
// steady state: entering PERIOD(Q), (xA0,xA1) holds step 4Q+4 data.
#define PERIOD(Q, PB)                                                          \
    {                                                                          \
        STEP(PB, 0, Q);                                                        \
        XLD2(xB0, xB1, 4 * (Q) + 5);                                           \
        STEP(PB, 1, Q);                                                        \
        XCM2((PB) ^ 1, 0, xA0, xA1);                                           \
        XLD2(xA0, xA1, 4 * (Q) + 6);                                           \
        STEP(PB, 2, Q);                                                        \
        XCM2((PB) ^ 1, 1, xB0, xB1);                                           \
        XLD2(xB0, xB1, 4 * (Q) + 7);                                           \
        STEP(PB, 3, Q);                                                        \
        XCM2((PB) ^ 1, 2, xA0, xA1);                                           \
        XLD2(xA0, xA1, 4 * (Q) + 8);   /* = 4(Q+1)+4: next period's sip0 */    \
        XCM2((PB) ^ 1, 3, xB0, xB1);                                           \
        BARRIER();                                                             \
    }

// ------------------------------- MFMA GEMM ----------------------------------
__global__ __launch_bounds__(512, 1) void mm_kernel(const float* __restrict__ x,
                                                    const uint8_t* __restrict__ Wb2,
                                                    const float* __restrict__ bias,
                                                    float* __restrict__ C) {
    __shared__ __attribute__((aligned(16))) uint8_t Af[2 * 16384];  // 32 KB
    const int t   = threadIdx.x;
    const int l   = t & 63;
    const int wv  = t >> 6;              // wave 0..7 -> cols wv*64..+63
    const int lr  = l & 31;
    const int hi  = l >> 5;
    const int row0 = blockIdx.x * MROWS;

    // x staging (verified): thread t owns rows trow & trow+32, f4 at tak
    const int trow = t >> 4;             // 0..31
    const int tak  = (t & 15) * 4;       // 0..60
    const int awk = (tak >> 5) * 1024
                  + (trow + 32 * ((tak >> 4) & 1)) * 16 + (tak & 15);
    const float* xr0 = x + (size_t)(row0 + trow) * KDIM + tak;
    // B base (verified): n5 = wv*2 + ct; ct stride 2048, ks stride 1024
    const uint8_t* bbase = Wb2 + ((size_t)(wv * 2) * 2 * 64 + l) * 16;

    v16i acc00, acc01, acc10, acc11;
    #pragma unroll
    for (int e = 0; e < 16; ++e) { acc00[e] = 0; acc01[e] = 0;
                                   acc10[e] = 0; acc11[e] = 0; }

    float4 xA0, xA1, xB0, xB1;

    // ---- prologue: stage steps 0..3 into Af[0]; preload xA = step 4 ----
    {
        float4 xa, xb;
        XLD2(xa, xb, 0); XCM2(0, 0, xa, xb);
        XLD2(xa, xb, 1); XCM2(0, 1, xa, xb);
        XLD2(xa, xb, 2); XCM2(0, 2, xa, xb);
        XLD2(xa, xb, 3); XCM2(0, 3, xa, xb);
        XLD2(xA0, xA1, 4);
        BARRIER();
    }

    #pragma unroll 1
    for (int q = 0; q < NPER; q += 2) {
        PERIOD(q,     0);
        PERIOD(q + 1, 1);
    }

    // ---- epilogue: C = acc + bias (verified C/D map) ----
    {
        const int col0 = wv * 64 + lr;          // ct = 0
        const int col1 = wv * 64 + 32 + lr;     // ct = 1
        const float bv0 = bias[col0], bv1 = bias[col1];
        #pragma unroll
        for (int r = 0; r < 16; ++r) {
            int crow = (r & 3) + 8 * (r >> 2) + 4 * hi;
            C[(size_t)(row0 + crow) * UNITS + col0]      = (float)acc00[r] + bv0;
            C[(size_t)(row0 + crow) * UNITS + col1]      = (float)acc01[r] + bv1;
            C[(size_t)(row0 + 32 + crow) * UNITS + col0] = (float)acc10[r] + bv0;
            C[(size_t)(row0 + 32 + crow) * UNITS + col1] = (float)acc11[r] + bv1;
        }
    }
}

extern "C" void kernel_launch(void* const* d_in, const int* in_sizes, int n_in,
                              void* d_out, int out_size, void* d_ws, size_t ws_size,
                              hipStream_t stream) {
    const float* x = (const float*)d_in[0];
    const float* W = (const float*)d_in[1];
    const float* b = (const float*)d_in[2];
    float* out = (float*)d_out;

    uint8_t* Wb2 = (uint8_t*)d_ws;   // 2 MB fragment-major packed W

    pack_w_kernel<<<(512 * 512) / 256, 256, 0, stream>>>(W, Wb2);
    mm_kernel<<<BATCH / MROWS, 512, 0, stream>>>(x, Wb2, b, out);
}

// Round 22
// 89.353 us; speedup vs baseline: 1.4405x; 1.0403x over previous
//
#include <hip/hip_runtime.h>
#include <stdint.h>

// Binarized dense via i8 MFMA: C[r][u] = dot(sign(x[r,:]), sign(W[:,u])) + b[u]
// sign in {+1,-1} as i8 0x01/0xFF; i32 accumulation exact (|dot| <= 4096).
// v_mfma_i32_32x32x32_i8: A/B = v4i (16 i8), lane&31 = row/col, lane>>5 =
// k-16-half; C/D: col = lane&31, row = (r&3)+8*(r>>2)+4*(lane>>5).
// Layouts/maps HW-verified (rounds 12-21, absmax 0).
//
// v18 = v17 (r21 best, 92.95us) with OCT-PERIODS: isolates the per-barrier
// fixed-cost hypothesis. Period = 8 K-steps instead of 4 -> barriers/kernel
// 16 -> 8; Af dbuf doubles to 64 KB (1 block/CU, fits). Everything else
// (per-step mix, on-demand B from L2 fragment-major Wb2, non-draining
// split-protocol barrier, 64x512 block, wave = 64x64) byte-identical.
// x-commit rotation: 2 named float4-pairs, one commit per step, >=1-step
// slack between load and commit; first commit's data loaded last period.

#define BATCH  16384
#define UNITS  512
#define KDIM   4096
#define KSTEP  64
#define NSTEP  (KDIM / KSTEP)   // 64
#define NPER8  (NSTEP / 8)      // 8 oct-periods
#define MROWS  64               // rows per block

typedef int v4i  __attribute__((ext_vector_type(4)));
typedef int v16i __attribute__((ext_vector_type(16)));

// split-protocol barrier: lgkm-drain only; vmcnt loads stay in flight
#define BARRIER()                                                              \
    do {                                                                       \
        asm volatile("s_waitcnt lgkmcnt(0)" ::: "memory");                     \
        __builtin_amdgcn_s_barrier();                                          \
        __builtin_amdgcn_sched_barrier(0);                                     \
    } while (0)

// ---- pack W: f32 [4096][512] -> Wb2 fragment-major i8 +/-1 (2 MB) ----------
// 16B chunk index ((s*16 + n5)*2 + ks)*64 + lane; lane = (n&31) + 32*k16half;
// covers col n5*32+(n&31), k = s*64 + ks*32 + k16half*16 + [0..15].
__global__ __launch_bounds__(256) void pack_w_kernel(const float* __restrict__ W,
                                                     uint8_t* __restrict__ Wb2) {
    int t  = blockIdx.x * 256 + threadIdx.x;   // 0..262143
    int n  = t & 511;                          // col
    int k0 = (t >> 9) * 8;                     // 8 consecutive k
    unsigned long long m = 0;
    #pragma unroll
    for (int j = 0; j < 8; ++j) {
        float v = W[(size_t)(k0 + j) * UNITS + n];
        m |= ((v < 0.f) ? 0xFFull : 0x01ull) << (8 * j);
    }
    int s  = k0 >> 6;
    int kk = k0 & 63;
    int ks = kk >> 5;
    int hi = (kk & 31) >> 4;
    int lane = (n & 31) + 32 * hi;
    size_t a = ((((size_t)s * 16 + (n >> 5)) * 2 + ks) * 64 + lane) * 16 + (kk & 15);
    *reinterpret_cast<unsigned long long*>(Wb2 + a) = m;
}

__device__ __forceinline__ uint32_t sgn4(float4 v) {
    uint32_t b0 = v.x < 0.f ? 0xFFu : 0x01u;
    uint32_t b1 = v.y < 0.f ? 0xFFu : 0x01u;
    uint32_t b2 = v.z < 0.f ? 0xFFu : 0x01u;
    uint32_t b3 = v.w < 0.f ? 0xFFu : 0x01u;
    return b0 | (b1 << 8) | (b2 << 16) | (b3 << 24);
}

// Af layout: byte = PB*32768 + sip*4096 + rt*2048 + ks*1024
//                 + ((row&31) + 32*k16half)*16 + off   (sip = 0..7)

// one K-step: 4 B-frags on demand (L2), 4 A-frags (2rt x 2ks), 8 MFMA
#define STEP(PB, SIP, Q)                                                       \
    {                                                                          \
        const uint8_t* _b = bbase + (size_t)(8 * (Q) + (SIP)) * 32768;         \
        v4i b0 = *reinterpret_cast<const v4i*>(_b);            /* ct0 ks0 */   \
        v4i b1 = *reinterpret_cast<const v4i*>(_b + 1024);     /* ct0 ks1 */   \
        v4i b2 = *reinterpret_cast<const v4i*>(_b + 2048);     /* ct1 ks0 */   \
        v4i b3 = *reinterpret_cast<const v4i*>(_b + 3072);     /* ct1 ks1 */   \
        const uint8_t* _a = &Af[(PB) * 32768 + (SIP) * 4096 + l * 16];         \
        v4i a00 = *reinterpret_cast<const v4i*>(_a);           /* rt0 ks0 */   \
        v4i a01 = *reinterpret_cast<const v4i*>(_a + 1024);    /* rt0 ks1 */   \
        v4i a10 = *reinterpret_cast<const v4i*>(_a + 2048);    /* rt1 ks0 */   \
        v4i a11 = *reinterpret_cast<const v4i*>(_a + 3072);    /* rt1 ks1 */   \
        __builtin_amdgcn_s_setprio(1);                                         \
        acc00 = __builtin_amdgcn_mfma_i32_32x32x32_i8(a00, b0, acc00, 0, 0, 0);\
        acc00 = __builtin_amdgcn_mfma_i32_32x32x32_i8(a01, b1, acc00, 0, 0, 0);\
        acc01 = __builtin_amdgcn_mfma_i32_32x32x32_i8(a00, b2, acc01, 0, 0, 0);\
        acc01 = __builtin_amdgcn_mfma_i32_32x32x32_i8(a01, b3, acc01, 0, 0, 0);\
        acc10 = __builtin_amdgcn_mfma_i32_32x32x32_i8(a10, b0, acc10, 0, 0, 0);\
        acc10 = __builtin_amdgcn_mfma_i32_32x32x32_i8(a11, b1, acc10, 0, 0, 0);\
        acc11 = __builtin_amdgcn_mfma_i32_32x32x32_i8(a10, b2, acc11, 0, 0, 0);\
        acc11 = __builtin_amdgcn_mfma_i32_32x32x32_i8(a11, b3, acc11, 0, 0, 0);\
        __builtin_amdgcn_s_setprio(0);                                         \
    }

// load this thread's 2 x-float4s (rows trow, trow+32) of absolute step S
#define XLD2(XA, XB, S)                                                        \
    {                                                                          \
        const int _sc = ((S) < NSTEP) ? (S) : NSTEP - 1;                       \
        XA = *reinterpret_cast<const float4*>(xr0 + (size_t)_sc * KSTEP);      \
        XB = *reinterpret_cast<const float4*>(xr0 + (size_t)32 * KDIM          \
                                                  + (size_t)_sc * KSTEP);      \
    }

// commit the pair into Af[PB], step-slot SIP (rt 0 and 1)
#define XCM2(PB, SIP, XA, XB)                                                  \
    {                                                                          \
        *reinterpret_cast<uint32_t*>(                                          \
            &Af[(PB) * 32768 + (SIP) * 4096 + awk]) = sgn4(XA);                \
        *reinterpret_cast<uint32_t*>(                                          \
            &Af[(PB) * 32768 + (SIP) * 4096 + 2048 + awk]) = sgn4(XB);         \
    }

// one oct-period: steps 8Q..8Q+7 read Af[PB]; commits A(8Q+8..+15) -> Af[PB^1]
// steady state: entering PERIOD(Q), (xA0,xA1) holds step 8Q+8 data.
#define PERIOD(Q, PB)                                                          \
    {                                                                          \
        STEP(PB, 0, Q);                                                        \
        XLD2(xB0, xB1, 8 * (Q) + 9);                                           \
        STEP(PB, 1, Q);                                                        \
        XCM2((PB) ^ 1, 0, xA0, xA1);                                           \
        XLD2(xA0, xA1, 8 * (Q) + 10);                                          \
        STEP(PB, 2, Q);                                                        \
        XCM2((PB) ^ 1, 1, xB0, xB1);                                           \
        XLD2(xB0, xB1, 8 * (Q) + 11);                                          \
        STEP(PB, 3, Q);                                                        \
        XCM2((PB) ^ 1, 2, xA0, xA1);                                           \
        XLD2(xA0, xA1, 8 * (Q) + 12);                                          \
        STEP(PB, 4, Q);                                                        \
        XCM2((PB) ^ 1, 3, xB0, xB1);                                           \
        XLD2(xB0, xB1, 8 * (Q) + 13);                                          \
        STEP(PB, 5, Q);                                                        \
        XCM2((PB) ^ 1, 4, xA0, xA1);                                           \
        XLD2(xA0, xA1, 8 * (Q) + 14);                                          \
        STEP(PB, 6, Q);                                                        \
        XCM2((PB) ^ 1, 5, xB0, xB1);                                           \
        XLD2(xB0, xB1, 8 * (Q) + 15);                                          \
        STEP(PB, 7, Q);                                                        \
        XCM2((PB) ^ 1, 6, xA0, xA1);                                           \
        XLD2(xA0, xA1, 8 * (Q) + 16);  /* = 8(Q+1)+8: next period's sip0 */    \
        XCM2((PB) ^ 1, 7, xB0, xB1);                                           \
        BARRIER();                                                             \
    }

// ------------------------------- MFMA GEMM ----------------------------------
__global__ __launch_bounds__(512, 1) void mm_kernel(const float* __restrict__ x,
                                                    const uint8_t* __restrict__ Wb2,
                                                    const float* __restrict__ bias,
                                                    float* __restrict__ C) {
    __shared__ __attribute__((aligned(16))) uint8_t Af[2 * 32768];  // 64 KB
    const int t   = threadIdx.x;
    const int l   = t & 63;
    const int wv  = t >> 6;              // wave 0..7 -> cols wv*64..+63
    const int lr  = l & 31;
    const int hi  = l >> 5;
    const int row0 = blockIdx.x * MROWS;

    // x staging (verified): thread t owns rows trow & trow+32, f4 at tak
    const int trow = t >> 4;             // 0..31
    const int tak  = (t & 15) * 4;       // 0..60
    const int awk = (tak >> 5) * 1024
                  + (trow + 32 * ((tak >> 4) & 1)) * 16 + (tak & 15);
    const float* xr0 = x + (size_t)(row0 + trow) * KDIM + tak;
    // B base (verified): n5 = wv*2 + ct; ct stride 2048, ks stride 1024
    const uint8_t* bbase = Wb2 + ((size_t)(wv * 2) * 2 * 64 + l) * 16;

    v16i acc00, acc01, acc10, acc11;
    #pragma unroll
    for (int e = 0; e < 16; ++e) { acc00[e] = 0; acc01[e] = 0;
                                   acc10[e] = 0; acc11[e] = 0; }

    float4 xA0, xA1, xB0, xB1;

    // ---- prologue: stage steps 0..7 into Af[0]; preload xA = step 8 ----
    {
        float4 xa, xb;
        XLD2(xa, xb, 0); XCM2(0, 0, xa, xb);
        XLD2(xa, xb, 1); XCM2(0, 1, xa, xb);
        XLD2(xa, xb, 2); XCM2(0, 2, xa, xb);
        XLD2(xa, xb, 3); XCM2(0, 3, xa, xb);
        XLD2(xa, xb, 4); XCM2(0, 4, xa, xb);
        XLD2(xa, xb, 5); XCM2(0, 5, xa, xb);
        XLD2(xa, xb, 6); XCM2(0, 6, xa, xb);
        XLD2(xa, xb, 7); XCM2(0, 7, xa, xb);
        XLD2(xA0, xA1, 8);
        BARRIER();
    }

    #pragma unroll 1
    for (int q = 0; q < NPER8; q += 2) {
        PERIOD(q,     0);
        PERIOD(q + 1, 1);
    }

    // ---- epilogue: C = acc + bias (verified C/D map) ----
    {
        const int col0 = wv * 64 + lr;          // ct = 0
        const int col1 = wv * 64 + 32 + lr;     // ct = 1
        const float bv0 = bias[col0], bv1 = bias[col1];
        #pragma unroll
        for (int r = 0; r < 16; ++r) {
            int crow = (r & 3) + 8 * (r >> 2) + 4 * hi;
            C[(size_t)(row0 + crow) * UNITS + col0]      = (float)acc00[r] + bv0;
            C[(size_t)(row0 + crow) * UNITS + col1]      = (float)acc01[r] + bv1;
            C[(size_t)(row0 + 32 + crow) * UNITS + col0] = (float)acc10[r] + bv0;
            C[(size_t)(row0 + 32 + crow) * UNITS + col1] = (float)acc11[r] + bv1;
        }
    }
}

extern "C" void kernel_launch(void* const* d_in, const int* in_sizes, int n_in,
                              void* d_out, int out_size, void* d_ws, size_t ws_size,
                              hipStream_t stream) {
    const float* x = (const float*)d_in[0];
    const float* W = (const float*)d_in[1];
    const float* b = (const float*)d_in[2];
    float* out = (float*)d_out;

    uint8_t* Wb2 = (uint8_t*)d_ws;   // 2 MB fragment-major packed W

    pack_w_kernel<<<(512 * 512) / 256, 256, 0, stream>>>(W, Wb2);
    mm_kernel<<<BATCH / MROWS, 512, 0, stream>>>(x, Wb2, b, out);
}